// Round 1
// baseline (126.533 us; speedup 1.0000x reference)
//
#include <hip/hip_runtime.h>
#include <math.h>

#define N_RAYS   262144
#define HIDDEN   256
#define NEAR_T   1.0f
#define FAR_T    10.0f
#define MAX_IT   64
#define EPS_T    1e-5f

// ---------------------------------------------------------------------------
// Pass 1: per-ray 64-iteration activity bitmask, global OR-reduce.
// bit i set  <=>  exists ray with (f_i > EPS) && mask_{i+1}
// ---------------------------------------------------------------------------
__global__ __launch_bounds__(256)
void st_trace_mask(const float* __restrict__ org,
                   const float* __restrict__ dir,
                   const float* __restrict__ center,
                   const float* __restrict__ radius,
                   unsigned long long* __restrict__ g_bits) {
    __shared__ unsigned long long s_or;
    if (threadIdx.x == 0) s_or = 0ull;
    __syncthreads();

    const int r = blockIdx.x * blockDim.x + threadIdx.x;

    const float cx = center[0], cy = center[1], cz = center[2];
    const float rad = radius[0];
    const float ox = org[3*r+0], oy = org[3*r+1], oz = org[3*r+2];
    const float dx = dir[3*r+0], dy = dir[3*r+1], dz = dir[3*r+2];

    float t  = NEAR_T;
    float px = ox + t*dx, py = oy + t*dy, pz = oz + t*dz;
    bool  m  = true;
    unsigned long long bits = 0ull;

    #pragma unroll
    for (int i = 0; i < MAX_IT; ++i) {
        const float fx = px - cx, fy = py - cy, fz = pz - cz;
        const float f  = sqrtf(fx*fx + fy*fy + fz*fz) - rad;
        const float tn = t + f;
        px = ox + tn*dx; py = oy + tn*dy; pz = oz + tn*dz;
        m  = m && (tn <= FAR_T);
        if ((f > EPS_T) && m) bits |= (1ull << i);
        t = tn;
    }

    atomicOr(&s_or, bits);        // LDS atomic, per-block reduce
    __syncthreads();
    if (threadIdx.x == 0) atomicOr(g_bits, s_or);
}

// ---------------------------------------------------------------------------
// Pass 2: derive global iteration count K, re-trace K iters, fused MLP.
// ---------------------------------------------------------------------------
__global__ __launch_bounds__(256)
void st_render(const float* __restrict__ org,
               const float* __restrict__ dir,
               const float* __restrict__ center,
               const float* __restrict__ radius,
               const float* __restrict__ w1,
               const float* __restrict__ b1,
               const float* __restrict__ w2,
               const float* __restrict__ b2,
               const unsigned long long* __restrict__ g_bits,
               float* __restrict__ out) {
    __shared__ float s_w1[3*HIDDEN];   // [3][256] row-major
    __shared__ float s_b1[HIDDEN];
    __shared__ float s_w2[HIDDEN*3];   // [256][3] row-major
    __shared__ float s_b2[3];

    for (int i = threadIdx.x; i < 3*HIDDEN; i += blockDim.x) s_w1[i] = w1[i];
    for (int i = threadIdx.x; i < HIDDEN;   i += blockDim.x) s_b1[i] = b1[i];
    for (int i = threadIdx.x; i < 3*HIDDEN; i += blockDim.x) s_w2[i] = w2[i];
    if (threadIdx.x < 3) s_b2[threadIdx.x] = b2[threadIdx.x];
    __syncthreads();

    const int r = blockIdx.x * blockDim.x + threadIdx.x;

    // Global applied-iteration count K (uniform across all threads).
    const unsigned long long bits  = *g_bits;
    const unsigned long long inact = ~bits;
    const int K = (inact == 0ull) ? MAX_IT : (__builtin_ctzll(inact) + 1);

    const float cx = center[0], cy = center[1], cz = center[2];
    const float rad = radius[0];
    const float ox = org[3*r+0], oy = org[3*r+1], oz = org[3*r+2];
    const float dx = dir[3*r+0], dy = dir[3*r+1], dz = dir[3*r+2];

    float t  = NEAR_T;
    float px = ox + t*dx, py = oy + t*dy, pz = oz + t*dz;
    bool  m  = true;

    for (int i = 0; i < K; ++i) {
        const float fx = px - cx, fy = py - cy, fz = pz - cz;
        const float f  = sqrtf(fx*fx + fy*fy + fz*fz) - rad;
        const float tn = t + f;
        px = ox + tn*dx; py = oy + tn*dy; pz = oz + tn*dz;
        m  = m && (tn <= FAR_T);
        t  = tn;
    }

    if (!m) {
        out[3*r+0] = 0.0f; out[3*r+1] = 0.0f; out[3*r+2] = 0.0f;
        return;
    }

    // Fused MLP: h = relu(p @ w1 + b1); rgb = sigmoid(h @ w2 + b2)
    float a0 = s_b2[0], a1 = s_b2[1], a2 = s_b2[2];
    #pragma unroll 8
    for (int j = 0; j < HIDDEN; ++j) {
        float h = px * s_w1[0*HIDDEN + j]
                + py * s_w1[1*HIDDEN + j]
                + pz * s_w1[2*HIDDEN + j]
                + s_b1[j];
        h = fmaxf(h, 0.0f);
        a0 += h * s_w2[3*j+0];
        a1 += h * s_w2[3*j+1];
        a2 += h * s_w2[3*j+2];
    }

    out[3*r+0] = 1.0f / (1.0f + expf(-a0));
    out[3*r+1] = 1.0f / (1.0f + expf(-a1));
    out[3*r+2] = 1.0f / (1.0f + expf(-a2));
}

// ---------------------------------------------------------------------------
extern "C" void kernel_launch(void* const* d_in, const int* in_sizes, int n_in,
                              void* d_out, int out_size, void* d_ws, size_t ws_size,
                              hipStream_t stream) {
    const float* org    = (const float*)d_in[0];
    const float* dir    = (const float*)d_in[1];
    const float* center = (const float*)d_in[2];
    const float* radius = (const float*)d_in[3];
    const float* w1     = (const float*)d_in[4];
    const float* b1     = (const float*)d_in[5];
    const float* w2     = (const float*)d_in[6];
    const float* b2     = (const float*)d_in[7];
    float* out = (float*)d_out;

    unsigned long long* g_bits = (unsigned long long*)d_ws;
    hipMemsetAsync(g_bits, 0, sizeof(unsigned long long), stream);

    const int block = 256;
    const int grid  = N_RAYS / block;   // 262144 / 256 = 1024

    st_trace_mask<<<grid, block, 0, stream>>>(org, dir, center, radius, g_bits);
    st_render<<<grid, block, 0, stream>>>(org, dir, center, radius,
                                          w1, b1, w2, b2, g_bits, out);
}

// Round 2
// 88.884 us; speedup vs baseline: 1.4236x; 1.4236x over previous
//
#include <hip/hip_runtime.h>
#include <math.h>

#define N_RAYS   262144
#define HIDDEN   256
#define NEAR_T   1.0f
#define FAR_T    10.0f
#define MAX_IT   64
#define EPS_T    1e-5f

// Fully fused: scalar-form sphere trace (64 iters, no global-stop pass needed:
// at any global stop point every ray is either converged (post-stop drift
// <= EPS/(1-kappa) ~ 1e-3 << 1.6e-2 tol) or escaped (masked to 0 anyway),
// and with 262k rays K=64 almost surely) + MLP with wave-uniform scalar
// weight loads (s_load on scalar pipe; zero LDS traffic).
__global__ __launch_bounds__(256)
void st_fused(const float* __restrict__ org,
              const float* __restrict__ dir,
              const float* __restrict__ center,
              const float* __restrict__ radius,
              const float* __restrict__ w1,
              const float* __restrict__ b1,
              const float* __restrict__ w2,
              const float* __restrict__ b2,
              float* __restrict__ out) {
    const int r = blockIdx.x * blockDim.x + threadIdx.x;

    const float cx = center[0], cy = center[1], cz = center[2];
    const float rad = radius[0];

    const float ox = org[3*r+0], oy = org[3*r+1], oz = org[3*r+2];
    const float dx = dir[3*r+0], dy = dir[3*r+1], dz = dir[3*r+2];

    // q = o - c;  B = q.d;  C = |q - B d|^2  (perp distance^2, cancellation-free)
    const float qx = ox - cx, qy = oy - cy, qz = oz - cz;
    const float B  = qx*dx + qy*dy + qz*dz;
    const float ex = __builtin_fmaf(-B, dx, qx);
    const float ey = __builtin_fmaf(-B, dy, qy);
    const float ez = __builtin_fmaf(-B, dz, qz);
    const float C  = ex*ex + ey*ey + ez*ez;

    // u = t + B;  f(t) = sqrt(u^2 + C) - rad;  u monotone increasing.
    float u = NEAR_T + B;
    #pragma unroll
    for (int i = 0; i < MAX_IT; ++i) {
        const float f = __builtin_amdgcn_sqrtf(__builtin_fmaf(u, u, C)) - rad;
        u += f;
    }
    const float t   = u - B;
    const bool  hit = (t <= FAR_T);   // t monotone => sticky mask == final test

    const float px = __builtin_fmaf(t, dx, ox);
    const float py = __builtin_fmaf(t, dy, oy);
    const float pz = __builtin_fmaf(t, dz, oz);

    // MLP: h = relu(p @ w1 + b1); rgb = sigmoid(h @ w2 + b2)
    // All weight indices are wave-uniform -> scalar loads (s_load), no LDS.
    float a0 = b2[0], a1 = b2[1], a2 = b2[2];
    #pragma unroll 16
    for (int j = 0; j < HIDDEN; ++j) {
        float h = __builtin_fmaf(px, w1[0*HIDDEN + j],
                  __builtin_fmaf(py, w1[1*HIDDEN + j],
                  __builtin_fmaf(pz, w1[2*HIDDEN + j], b1[j])));
        h = fmaxf(h, 0.0f);
        a0 = __builtin_fmaf(h, w2[3*j+0], a0);
        a1 = __builtin_fmaf(h, w2[3*j+1], a1);
        a2 = __builtin_fmaf(h, w2[3*j+2], a2);
    }

    const float s0 = 1.0f / (1.0f + __expf(-a0));
    const float s1 = 1.0f / (1.0f + __expf(-a1));
    const float s2 = 1.0f / (1.0f + __expf(-a2));

    out[3*r+0] = hit ? s0 : 0.0f;
    out[3*r+1] = hit ? s1 : 0.0f;
    out[3*r+2] = hit ? s2 : 0.0f;
}

extern "C" void kernel_launch(void* const* d_in, const int* in_sizes, int n_in,
                              void* d_out, int out_size, void* d_ws, size_t ws_size,
                              hipStream_t stream) {
    const float* org    = (const float*)d_in[0];
    const float* dir    = (const float*)d_in[1];
    const float* center = (const float*)d_in[2];
    const float* radius = (const float*)d_in[3];
    const float* w1     = (const float*)d_in[4];
    const float* b1     = (const float*)d_in[5];
    const float* w2     = (const float*)d_in[6];
    const float* b2     = (const float*)d_in[7];
    float* out = (float*)d_out;

    const int block = 256;
    const int grid  = N_RAYS / block;   // 1024

    st_fused<<<grid, block, 0, stream>>>(org, dir, center, radius,
                                         w1, b1, w2, b2, out);
}